// Round 11
// baseline (76.822 us; speedup 1.0000x reference)
//
#include <hip/hip_runtime.h>
#include <math.h>

// ContactModel R11: champion flow + ALL input loads as aligned float4
// (deliberate over-read within the row). Touched windows per row:
//   joints floats 12..19, 24..35   -> 5 x float4 (bytes 48,64,96,112,128; row
//                                     stride 288 = 18*16 so all 16B-aligned)
//   jori   floats 36..55, 80..99   -> 10 x float4 (bytes 144..,320..; row
//                                     stride 864 = 54*16, aligned)
// 30 dwordx4 per thread (both rows) vs ~40 mixed-width before: fewer VMEM
// queue slots, same cache lines, same HBM traffic. Unpack + all math/stores
// byte-identical to the R1/R6/R10 champion (67.1-67.4 us, absmax 524288).

__device__ __constant__ float c_local[12][3] = {
    {0.00190115788407966f, -0.01f, -0.00382630379623308f},
    {0.148386399942063f,   -0.01f, -0.028713422052654f},
    {0.133001170607051f,   -0.01f,  0.0516362473449566f},
    {0.0662346661991635f,  -0.01f,  0.0263641606741698f},
    {0.06f,                -0.01f, -0.0187603084619177f},
    {0.045f,               -0.01f,  0.0618569567549652f},
    {0.00190115788407966f, -0.01f,  0.00382630379623308f},
    {0.148386399942063f,   -0.01f,  0.028713422052654f},
    {0.133001170607051f,   -0.01f, -0.0516362473449566f},
    {0.0662346661991635f,  -0.01f, -0.0263641606741698f},
    {0.06f,                -0.01f,  0.0187603084619177f},
    {0.045f,               -0.01f, -0.0618569567549652f}};

// Load one batch row's touched inputs as 15 aligned float4s and unpack into
// J[12] (bodies 4,5,9,10 xyz) and M[36] (their 3x3 orientations, row-major).
__device__ __forceinline__ void load_row_f4(const float* __restrict__ jrow,
                                            const float* __restrict__ mrow,
                                            float* J, float* M)
{
    const float4 q0 = *reinterpret_cast<const float4*>(jrow + 12);  // 12-15
    const float4 q1 = *reinterpret_cast<const float4*>(jrow + 16);  // 16-19
    const float4 q2 = *reinterpret_cast<const float4*>(jrow + 24);  // 24-27
    const float4 q3 = *reinterpret_cast<const float4*>(jrow + 28);  // 28-31
    const float4 q4 = *reinterpret_cast<const float4*>(jrow + 32);  // 32-35
    const float4 r0 = *reinterpret_cast<const float4*>(mrow + 36);  // 36-39
    const float4 r1 = *reinterpret_cast<const float4*>(mrow + 40);  // 40-43
    const float4 r2 = *reinterpret_cast<const float4*>(mrow + 44);  // 44-47
    const float4 r3 = *reinterpret_cast<const float4*>(mrow + 48);  // 48-51
    const float4 r4 = *reinterpret_cast<const float4*>(mrow + 52);  // 52-55
    const float4 s0 = *reinterpret_cast<const float4*>(mrow + 80);  // 80-83
    const float4 s1 = *reinterpret_cast<const float4*>(mrow + 84);  // 84-87
    const float4 s2 = *reinterpret_cast<const float4*>(mrow + 88);  // 88-91
    const float4 s3 = *reinterpret_cast<const float4*>(mrow + 92);  // 92-95
    const float4 s4 = *reinterpret_cast<const float4*>(mrow + 96);  // 96-99

    // body 4 pos = floats 12,13,14 ; body 5 = 15,16,17
    J[0]=q0.x; J[1]=q0.y; J[2]=q0.z;
    J[3]=q0.w; J[4]=q1.x; J[5]=q1.y;
    // body 9 pos = floats 27,28,29 ; body 10 = 30,31,32
    J[6]=q2.w; J[7]=q3.x; J[8]=q3.y;
    J[9]=q3.z; J[10]=q3.w; J[11]=q4.x;

    // body 4 ori = jori floats 36..44
    M[0]=r0.x; M[1]=r0.y; M[2]=r0.z; M[3]=r0.w; M[4]=r1.x; M[5]=r1.y; M[6]=r1.z; M[7]=r1.w; M[8]=r2.x;
    // body 5 ori = 45..53
    M[9]=r2.y; M[10]=r2.z; M[11]=r2.w; M[12]=r3.x; M[13]=r3.y; M[14]=r3.z; M[15]=r3.w; M[16]=r4.x; M[17]=r4.y;
    // body 9 ori = 81..89
    M[18]=s0.y; M[19]=s0.z; M[20]=s0.w; M[21]=s1.x; M[22]=s1.y; M[23]=s1.z; M[24]=s1.w; M[25]=s2.x; M[26]=s2.y;
    // body 10 ori = 90..98
    M[27]=s2.z; M[28]=s2.w; M[29]=s3.x; M[30]=s3.y; M[31]=s3.z; M[32]=s3.w; M[33]=s4.x; M[34]=s4.y; M[35]=s4.z;
}

__global__ __launch_bounds__(256)
void contact_kernel(const float* __restrict__ joints,
                    const float* __restrict__ jori,
                    float* __restrict__ out, const int B)
{
    const int b = blockIdx.x * blockDim.x + threadIdx.x;
    if (b >= B) return;

    const int bp = (b > 0) ? (b - 1) : b;   // bp==b => vel exactly 0 (ref)

    // ---- PHASE 1: all loads as aligned float4 ----
    float J[12], M[36];     // own row
    float P[12], N[36];     // prev row
    load_row_f4(joints + (size_t)b  * 72, jori + (size_t)b  * 216, J, M);
    load_row_f4(joints + (size_t)bp * 72, jori + (size_t)bp * 216, P, N);

    // ---- PHASE 2: positions + velocity ----
    float px[12], py[12], pz[12];
    float fx[12], fy[12], fz[12];   // velocity first, then force in-place
    {
        const int sbeg[4] = {0, 4, 6, 10};
        const int scnt[4] = {4, 2, 4, 2};
        #pragma unroll
        for (int bi = 0; bi < 4; ++bi) {
            const float jx = J[bi*3+0], jy = J[bi*3+1], jz = J[bi*3+2];
            const float kx = P[bi*3+0], ky = P[bi*3+1], kz = P[bi*3+2];
            const float m00=M[bi*9+0],m01=M[bi*9+1],m02=M[bi*9+2];
            const float m10=M[bi*9+3],m11=M[bi*9+4],m12=M[bi*9+5];
            const float m20=M[bi*9+6],m21=M[bi*9+7],m22=M[bi*9+8];
            const float n00=N[bi*9+0],n01=N[bi*9+1],n02=N[bi*9+2];
            const float n10=N[bi*9+3],n11=N[bi*9+4],n12=N[bi*9+5];
            const float n20=N[bi*9+6],n21=N[bi*9+7],n22=N[bi*9+8];
            #pragma unroll
            for (int si = 0; si < 4; ++si) {
                if (si < scnt[bi]) {
                    const int s = sbeg[bi] + si;
                    const float lx = c_local[s][0];
                    const float ly = c_local[s][1];
                    const float lz = c_local[s][2];
                    const float ax = jx + m00*lx + m01*ly + m02*lz;
                    const float ay = jy + m10*lx + m11*ly + m12*lz;
                    const float az = jz + m20*lx + m21*ly + m22*lz;
                    const float bx = kx + n00*lx + n01*ly + n02*lz;
                    const float by = ky + n10*lx + n11*ly + n12*lz;
                    const float bz = kz + n20*lx + n21*ly + n22*lz;
                    px[s] = ax; py[s] = ay; pz[s] = az;
                    fx[s] = (ax - bx) * 20.0f;   // 1/DT = 20
                    fy[s] = (ay - by) * 20.0f;
                    fz[s] = (az - bz) * 20.0f;
                }
            }
        }
    }

    // ---- PHASE 3: contact forces (champion numerics, in-place) ----
    const float KF  = 1077.21734501594f;                 // 0.5 * 100000**(2/3)
    const float CFH = (4.0f/3.0f) * KF * sqrtf(0.032f * KF);
    #pragma unroll
    for (int s = 0; s < 12; ++s) {
        const float vx = fx[s], vy = fy[s], vz = fz[s];
        const float ind     = -py[s];                    // GROUND_HEIGHT = 0
        const float ind_vel = -vy;
        const float q   = ind*ind + 1e-5f;
        const float fH  = CFH * sqrtf(q * sqrtf(q));     // q^0.75
        const float fHd = fH * (1.0f + 0.3f * ind_vel);  // 1.5*DISSIPATION = 0.3
        const float t1 = (0.5f*tanhf(50.0f*(ind_vel + 3.3333333333333335f)) + 0.5f) + 1e-16f;
        const float t2 = (0.5f*tanhf(300.0f*ind) + 0.5f) + 1e-16f;
        const float fn = t1 * t2 * fHd;
        const float vslip = sqrtf(vx*vx + vz*vz + 1e-5f);
        const float vrel  = vslip * 5.0f;                // / TRANSITION_VELOCITY
        // STATIC==DYNAMIC==0.8 -> 2*(S-D)/(1+vrel^2) term is exactly 0
        const float mu  = fminf(vrel, 1.0f) * 0.8f + 0.5f * vslip;
        const float ffr = fn * mu;
        const float sc  = ffr / (vslip + 1e-5f);
        fx[s] = -sc * vx;
        fy[s] = fn;
        fz[s] = -sc * vz;
    }

    // ---- group reductions: g=0 all, g=1 right(0..6), g=2 left(6..12) ----
    float res[3][9];
    const int gs0[3] = {0, 0, 6};
    const int gs1[3] = {12, 6, 12};
    #pragma unroll
    for (int g = 0; g < 3; ++g) {
        float Fx=0.f, Fy=0.f, Fz=0.f, tw=0.f, sx=0.f, sz=0.f;
        #pragma unroll
        for (int s = 0; s < 12; ++s) {
            if (s >= gs0[g] && s < gs1[g]) {
                Fx += fx[s]; Fy += fy[s]; Fz += fz[s];
                const float w = fy[s] > 0.f ? fy[s] : 0.f;
                tw += w;
                sx += px[s] * w;
                sz += pz[s] * w;
            }
        }
        const bool has = tw > 0.f;
        const float cx = has ? sx / tw : 0.f;
        const float cz = has ? sz / tw : 0.f;
        float Tx=0.f, Ty=0.f, Tz=0.f;
        #pragma unroll
        for (int s = 0; s < 12; ++s) {
            if (s >= gs0[g] && s < gs1[g]) {
                if (fy[s] > 0.f) {
                    const float rx = px[s]-cx, ry = py[s], rz = pz[s]-cz;  // cy==0
                    Tx += ry*fz[s] - rz*fy[s];
                    Ty += rz*fx[s] - rx*fz[s];
                    Tz += rx*fy[s] - ry*fx[s];
                }
            }
        }
        res[g][0]=Fx; res[g][1]=Fy; res[g][2]=Fz;
        res[g][3]=Tx; res[g][4]=Ty; res[g][5]=Tz;
        res[g][6]=cx; res[g][7]=0.f; res[g][8]=cz;
    }

    // ---- stores (champion layout) ----
    const size_t sB = (size_t)B;
    const size_t t3 = (size_t)b * 3;
    float* o;
    o = out;           o[t3]=res[0][0]; o[t3+1]=res[0][1]; o[t3+2]=res[0][2];
    o = out + sB*3;    o[t3]=res[0][3]; o[t3+1]=res[0][4]; o[t3+2]=res[0][5];
    o = out + sB*6;    o[t3]=res[0][6]; o[t3+1]=res[0][7]; o[t3+2]=res[0][8];
    o = out + sB*81;   o[t3]=res[1][0]; o[t3+1]=res[1][1]; o[t3+2]=res[1][2];
    o = out + sB*84;   o[t3]=res[2][0]; o[t3+1]=res[2][1]; o[t3+2]=res[2][2];
    o = out + sB*87;   o[t3]=res[1][3]; o[t3+1]=res[1][4]; o[t3+2]=res[1][5];
    o = out + sB*90;   o[t3]=res[2][3]; o[t3+1]=res[2][4]; o[t3+2]=res[2][5];
    o = out + sB*93;   o[t3]=res[1][6]; o[t3+1]=res[1][7]; o[t3+2]=res[1][8];
    o = out + sB*96;   o[t3]=res[2][6]; o[t3+1]=res[2][7]; o[t3+2]=res[2][8];

    float* osf = out + sB*9  + (size_t)b*36;
    float* opp = out + sB*45 + (size_t)b*36;
    if ((B & 3) == 0) {  // 16B alignment guaranteed
        float bufF[36], bufP[36];
        #pragma unroll
        for (int s = 0; s < 12; ++s) {
            bufF[s*3+0]=fx[s]; bufF[s*3+1]=fy[s]; bufF[s*3+2]=fz[s];
            bufP[s*3+0]=px[s]; bufP[s*3+1]=py[s]; bufP[s*3+2]=pz[s];
        }
        #pragma unroll
        for (int i = 0; i < 9; ++i) {
            reinterpret_cast<float4*>(osf)[i] = reinterpret_cast<float4*>(bufF)[i];
            reinterpret_cast<float4*>(opp)[i] = reinterpret_cast<float4*>(bufP)[i];
        }
    } else {
        #pragma unroll
        for (int s = 0; s < 12; ++s) {
            osf[s*3+0]=fx[s]; osf[s*3+1]=fy[s]; osf[s*3+2]=fz[s];
            opp[s*3+0]=px[s]; opp[s*3+1]=py[s]; opp[s*3+2]=pz[s];
        }
    }
}

extern "C" void kernel_launch(void* const* d_in, const int* in_sizes, int n_in,
                              void* d_out, int out_size, void* d_ws, size_t ws_size,
                              hipStream_t stream) {
    const float* joints = (const float*)d_in[0];
    const float* jori   = (const float*)d_in[1];
    float* out = (float*)d_out;
    const int B = in_sizes[0] / 72;   // joints is (B, 24, 3)
    const int block = 256;
    const int grid  = (B + block - 1) / block;
    contact_kernel<<<grid, block, 0, stream>>>(joints, jori, out, B);
}

// Round 12
// 63.465 us; speedup vs baseline: 1.2105x; 1.2105x over previous
//
#include <hip/hip_runtime.h>
#include <math.h>

// ContactModel R12: champion loads/compute + LDS-transposed coalesced stores
// for the two 36-float-per-batch arrays (sphere_forces, pos).
// Champion wrote them as 18 float4 @ 144B lane stride = 64 L1 segments per
// instruction (1152 segments/wave, 4x the 288 minimum). Here each block
// stages one array in LDS (stride 37: (37t+c)%32 -> 2 lanes/bank = free) and
// streams it out block-contiguously (16 segments per instruction). Staging
// happens AFTER all loads/compute (unlike R4's read-staging failure): load
// schedule untouched, occupancy unchanged (37888 B LDS x 4 blocks < 160 KB).

__device__ __constant__ float c_local[12][3] = {
    {0.00190115788407966f, -0.01f, -0.00382630379623308f},
    {0.148386399942063f,   -0.01f, -0.028713422052654f},
    {0.133001170607051f,   -0.01f,  0.0516362473449566f},
    {0.0662346661991635f,  -0.01f,  0.0263641606741698f},
    {0.06f,                -0.01f, -0.0187603084619177f},
    {0.045f,               -0.01f,  0.0618569567549652f},
    {0.00190115788407966f, -0.01f,  0.00382630379623308f},
    {0.148386399942063f,   -0.01f,  0.028713422052654f},
    {0.133001170607051f,   -0.01f, -0.0516362473449566f},
    {0.0662346661991635f,  -0.01f, -0.0263641606741698f},
    {0.06f,                -0.01f,  0.0187603084619177f},
    {0.045f,               -0.01f, -0.0618569567549652f}};

__global__ __launch_bounds__(256)
void contact_kernel(const float* __restrict__ joints,
                    const float* __restrict__ jori,
                    float* __restrict__ out, const int B)
{
    __shared__ float sbuf[256 * 37];
    const int tid = threadIdx.x;
    const int b = blockIdx.x * blockDim.x + tid;
    const bool full = ((B & 255) == 0);   // block-uniform: barriers safe
    if (b >= B) return;                   // with full=true no thread exits

    float px[12], py[12], pz[12];
    float fx[12], fy[12], fz[12];   // velocity first, then force in-place

    {
        const int bodies[4] = {4, 5, 9, 10};
        const int sbeg[4]   = {0, 4, 6, 10};
        const int scnt[4]   = {4, 2, 4, 2};
        const int bp = (b > 0) ? (b - 1) : b;   // bp==b => vel exactly 0 (ref)
        const float* jr  = joints + (size_t)b  * 72;
        const float* jrp = joints + (size_t)bp * 72;
        const float* mr  = jori   + (size_t)b  * 216;
        const float* mrp = jori   + (size_t)bp * 216;

        #pragma unroll
        for (int bi = 0; bi < 4; ++bi) {
            const int body = bodies[bi];
            const float jx = jr[body*3+0], jy = jr[body*3+1], jz = jr[body*3+2];
            const float* m = mr + body*9;
            const float m00=m[0],m01=m[1],m02=m[2];
            const float m10=m[3],m11=m[4],m12=m[5];
            const float m20=m[6],m21=m[7],m22=m[8];
            const float kx = jrp[body*3+0], ky = jrp[body*3+1], kz = jrp[body*3+2];
            const float* nn = mrp + body*9;
            const float n00=nn[0],n01=nn[1],n02=nn[2];
            const float n10=nn[3],n11=nn[4],n12=nn[5];
            const float n20=nn[6],n21=nn[7],n22=nn[8];
            #pragma unroll
            for (int si = 0; si < 4; ++si) {
                if (si < scnt[bi]) {
                    const int s = sbeg[bi] + si;
                    const float lx = c_local[s][0];
                    const float ly = c_local[s][1];
                    const float lz = c_local[s][2];
                    const float ax = jx + m00*lx + m01*ly + m02*lz;
                    const float ay = jy + m10*lx + m11*ly + m12*lz;
                    const float az = jz + m20*lx + m21*ly + m22*lz;
                    const float bx = kx + n00*lx + n01*ly + n02*lz;
                    const float by = ky + n10*lx + n11*ly + n12*lz;
                    const float bz = kz + n20*lx + n21*ly + n22*lz;
                    px[s] = ax; py[s] = ay; pz[s] = az;
                    fx[s] = (ax - bx) * 20.0f;   // 1/DT = 20
                    fy[s] = (ay - by) * 20.0f;
                    fz[s] = (az - bz) * 20.0f;
                }
            }
        }
    }

    // ---- contact forces (champion numerics, in-place over velocity) ----
    const float KF  = 1077.21734501594f;                 // 0.5 * 100000**(2/3)
    const float CFH = (4.0f/3.0f) * KF * sqrtf(0.032f * KF);
    #pragma unroll
    for (int s = 0; s < 12; ++s) {
        const float vx = fx[s], vy = fy[s], vz = fz[s];
        const float ind     = -py[s];                    // GROUND_HEIGHT = 0
        const float ind_vel = -vy;
        const float q   = ind*ind + 1e-5f;
        const float fH  = CFH * sqrtf(q * sqrtf(q));     // q^0.75
        const float fHd = fH * (1.0f + 0.3f * ind_vel);  // 1.5*DISSIPATION = 0.3
        const float t1 = (0.5f*tanhf(50.0f*(ind_vel + 3.3333333333333335f)) + 0.5f) + 1e-16f;
        const float t2 = (0.5f*tanhf(300.0f*ind) + 0.5f) + 1e-16f;
        const float fn = t1 * t2 * fHd;
        const float vslip = sqrtf(vx*vx + vz*vz + 1e-5f);
        const float vrel  = vslip * 5.0f;                // / TRANSITION_VELOCITY
        // STATIC==DYNAMIC==0.8 -> 2*(S-D)/(1+vrel^2) term is exactly 0
        const float mu  = fminf(vrel, 1.0f) * 0.8f + 0.5f * vslip;
        const float ffr = fn * mu;
        const float sc  = ffr / (vslip + 1e-5f);
        fx[s] = -sc * vx;
        fy[s] = fn;
        fz[s] = -sc * vz;
    }

    // ---- group reductions (champion code) ----
    float res[3][9];
    const int gs0[3] = {0, 0, 6};
    const int gs1[3] = {12, 6, 12};
    #pragma unroll
    for (int g = 0; g < 3; ++g) {
        float Fx=0.f, Fy=0.f, Fz=0.f, tw=0.f, sx=0.f, sz=0.f;
        #pragma unroll
        for (int s = 0; s < 12; ++s) {
            if (s >= gs0[g] && s < gs1[g]) {
                Fx += fx[s]; Fy += fy[s]; Fz += fz[s];
                const float w = fy[s] > 0.f ? fy[s] : 0.f;
                tw += w;
                sx += px[s] * w;
                sz += pz[s] * w;
            }
        }
        const bool has = tw > 0.f;
        const float cx = has ? sx / tw : 0.f;
        const float cz = has ? sz / tw : 0.f;
        float Tx=0.f, Ty=0.f, Tz=0.f;
        #pragma unroll
        for (int s = 0; s < 12; ++s) {
            if (s >= gs0[g] && s < gs1[g]) {
                if (fy[s] > 0.f) {
                    const float rx = px[s]-cx, ry = py[s], rz = pz[s]-cz;  // cy==0
                    Tx += ry*fz[s] - rz*fy[s];
                    Ty += rz*fx[s] - rx*fz[s];
                    Tz += rx*fy[s] - ry*fx[s];
                }
            }
        }
        res[g][0]=Fx; res[g][1]=Fy; res[g][2]=Fz;
        res[g][3]=Tx; res[g][4]=Ty; res[g][5]=Tz;
        res[g][6]=cx; res[g][7]=0.f; res[g][8]=cz;
    }

    // ---- small-region stores (already segment-minimal, unchanged) ----
    const size_t sB = (size_t)B;
    const size_t t3 = (size_t)b * 3;
    float* o;
    o = out;           o[t3]=res[0][0]; o[t3+1]=res[0][1]; o[t3+2]=res[0][2];
    o = out + sB*3;    o[t3]=res[0][3]; o[t3+1]=res[0][4]; o[t3+2]=res[0][5];
    o = out + sB*6;    o[t3]=res[0][6]; o[t3+1]=res[0][7]; o[t3+2]=res[0][8];
    o = out + sB*81;   o[t3]=res[1][0]; o[t3+1]=res[1][1]; o[t3+2]=res[1][2];
    o = out + sB*84;   o[t3]=res[2][0]; o[t3+1]=res[2][1]; o[t3+2]=res[2][2];
    o = out + sB*87;   o[t3]=res[1][3]; o[t3+1]=res[1][4]; o[t3+2]=res[1][5];
    o = out + sB*90;   o[t3]=res[2][3]; o[t3+1]=res[2][4]; o[t3+2]=res[2][5];
    o = out + sB*93;   o[t3]=res[1][6]; o[t3+1]=res[1][7]; o[t3+2]=res[1][8];
    o = out + sB*96;   o[t3]=res[2][6]; o[t3+1]=res[2][7]; o[t3+2]=res[2][8];

    // ---- big-array stores: LDS transpose -> block-contiguous float4 ----
    if (full) {
        // array 1: sphere_forces
        #pragma unroll
        for (int s = 0; s < 12; ++s) {
            sbuf[tid*37 + s*3+0] = fx[s];
            sbuf[tid*37 + s*3+1] = fy[s];
            sbuf[tid*37 + s*3+2] = fz[s];
        }
        __syncthreads();
        {
            float4* dst = reinterpret_cast<float4*>(out + sB*9) + (size_t)blockIdx.x*2304;
            #pragma unroll
            for (int i = 0; i < 9; ++i) {
                const int j = tid + 256*i;          // float4 idx in block tile
                const int g = 4*j;                  // float idx
                float v[4];
                #pragma unroll
                for (int e = 0; e < 4; ++e) {
                    const int gg = g+e; const int r = gg/36; const int c = gg-r*36;
                    v[e] = sbuf[r*37+c];
                }
                dst[j] = make_float4(v[0],v[1],v[2],v[3]);
            }
        }
        __syncthreads();
        // array 2: pos
        #pragma unroll
        for (int s = 0; s < 12; ++s) {
            sbuf[tid*37 + s*3+0] = px[s];
            sbuf[tid*37 + s*3+1] = py[s];
            sbuf[tid*37 + s*3+2] = pz[s];
        }
        __syncthreads();
        {
            float4* dst = reinterpret_cast<float4*>(out + sB*45) + (size_t)blockIdx.x*2304;
            #pragma unroll
            for (int i = 0; i < 9; ++i) {
                const int j = tid + 256*i;
                const int g = 4*j;
                float v[4];
                #pragma unroll
                for (int e = 0; e < 4; ++e) {
                    const int gg = g+e; const int r = gg/36; const int c = gg-r*36;
                    v[e] = sbuf[r*37+c];
                }
                dst[j] = make_float4(v[0],v[1],v[2],v[3]);
            }
        }
    } else {
        float* osf = out + sB*9  + (size_t)b*36;
        float* opp = out + sB*45 + (size_t)b*36;
        #pragma unroll
        for (int s = 0; s < 12; ++s) {
            osf[s*3+0]=fx[s]; osf[s*3+1]=fy[s]; osf[s*3+2]=fz[s];
            opp[s*3+0]=px[s]; opp[s*3+1]=py[s]; opp[s*3+2]=pz[s];
        }
    }
}

extern "C" void kernel_launch(void* const* d_in, const int* in_sizes, int n_in,
                              void* d_out, int out_size, void* d_ws, size_t ws_size,
                              hipStream_t stream) {
    const float* joints = (const float*)d_in[0];
    const float* jori   = (const float*)d_in[1];
    float* out = (float*)d_out;
    const int B = in_sizes[0] / 72;   // joints is (B, 24, 3)
    const int block = 256;
    const int grid  = (B + block - 1) / block;
    contact_kernel<<<grid, block, 0, stream>>>(joints, jori, out, B);
}